// Round 1
// baseline (301.215 us; speedup 1.0000x reference)
//
#include <hip/hip_runtime.h>
#include <math.h>

#define N_POS 4096
#define C_DIM 528
#define NHEAD 8
#define HDIM  66
#define KNN   32
#define CQKV  1584   // 3*C

// ---------------------------------------------------------------------------
// C[m][n] = sum_k A[m][k] * B[n][k] + bias[n]   (A: MxK row-major, B: NxK row-major)
// BM=BN=64, BK=16, 256 threads, 4x4 micro-tile per thread.
// M must be a multiple of 64; K a multiple of 16; N guarded.
// ---------------------------------------------------------------------------
__global__ __launch_bounds__(256) void gemm_bt_kernel(
    const float* __restrict__ A, const float* __restrict__ B,
    const float* __restrict__ bias, float* __restrict__ C,
    int M, int N, int Kd)
{
    const int BM = 64, BN = 64, BK = 16;
    __shared__ float As[BK][BM];
    __shared__ float Bs[BK][BN];

    int tid = threadIdx.x;
    int bm = blockIdx.y * BM;
    int bn = blockIdx.x * BN;
    int tx = tid & 15;       // 0..15  -> 4 cols each
    int ty = tid >> 4;       // 0..15  -> 4 rows each
    int lr = tid >> 2;       // 0..63  load row
    int lc = (tid & 3) * 4;  // 0,4,8,12 load col (k)

    float acc[4][4] = {};

    for (int k0 = 0; k0 < Kd; k0 += BK) {
        float4 va = *(const float4*)(A + (size_t)(bm + lr) * Kd + k0 + lc);
        As[lc + 0][lr] = va.x; As[lc + 1][lr] = va.y;
        As[lc + 2][lr] = va.z; As[lc + 3][lr] = va.w;

        float4 vb = make_float4(0.f, 0.f, 0.f, 0.f);
        if (bn + lr < N)
            vb = *(const float4*)(B + (size_t)(bn + lr) * Kd + k0 + lc);
        Bs[lc + 0][lr] = vb.x; Bs[lc + 1][lr] = vb.y;
        Bs[lc + 2][lr] = vb.z; Bs[lc + 3][lr] = vb.w;

        __syncthreads();

        #pragma unroll
        for (int kk = 0; kk < BK; ++kk) {
            float a[4], b[4];
            #pragma unroll
            for (int i = 0; i < 4; ++i) a[i] = As[kk][ty * 4 + i];
            #pragma unroll
            for (int j = 0; j < 4; ++j) b[j] = Bs[kk][tx * 4 + j];
            #pragma unroll
            for (int i = 0; i < 4; ++i)
                #pragma unroll
                for (int j = 0; j < 4; ++j)
                    acc[i][j] += a[i] * b[j];
        }
        __syncthreads();
    }

    #pragma unroll
    for (int i = 0; i < 4; ++i) {
        int row = bm + ty * 4 + i;
        #pragma unroll
        for (int j = 0; j < 4; ++j) {
            int col = bn + tx * 4 + j;
            if (col < N)
                C[(size_t)row * N + col] = acc[i][j] + bias[col];
        }
    }
}

// ---------------------------------------------------------------------------
// Fused l2norm + 33-key attention.  One block (256 thr) per (h, n).
// qkv: [N_POS][CQKV]  (col = t*528 + h*66 + d, t in {q,k,v})
// knn: [NHEAD][N_POS][KNN][2][HDIM]
// out: [N_POS][C_DIM]  (col = h*66 + d)
// ---------------------------------------------------------------------------
__global__ __launch_bounds__(256) void attn_kernel(
    const float* __restrict__ qkv, const float* __restrict__ knn,
    float* __restrict__ out)
{
    const float scaling = 0.12309149097933272f;  // 66^-0.5

    int bid = blockIdx.x;
    int h = bid >> 12;        // / 4096
    int n = bid & 4095;
    int tid = threadIdx.x;

    __shared__ float s_knn[KNN * 2 * HDIM];   // 4224 floats
    __shared__ float s_q[HDIM], s_k[HDIM], s_v[HDIM];
    __shared__ float s_dot[KNN + 1];
    __shared__ float s_scale[2];

    // stage knn block (16.9 KB), coalesced float4
    {
        const float4* src = (const float4*)(knn + ((size_t)bid) * (KNN * 2 * HDIM));
        float4* dst = (float4*)s_knn;
        for (int i = tid; i < KNN * 2 * HDIM / 4; i += 256) dst[i] = src[i];
    }
    const float* qp = qkv + (size_t)n * CQKV + h * HDIM;
    if (tid < HDIM) {
        s_q[tid] = qp[tid];
        s_k[tid] = qp[C_DIM + tid];
        s_v[tid] = qp[2 * C_DIM + tid];
    }
    __syncthreads();

    // L2 norms of q and k (wave 0)
    if (tid < 64) {
        float aq = s_q[tid] * s_q[tid];
        float ak = s_k[tid] * s_k[tid];
        if (tid < 2) {
            aq += s_q[64 + tid] * s_q[64 + tid];
            ak += s_k[64 + tid] * s_k[64 + tid];
        }
        #pragma unroll
        for (int off = 32; off; off >>= 1) {
            aq += __shfl_xor(aq, off);
            ak += __shfl_xor(ak, off);
        }
        if (tid == 0) {
            s_scale[0] = 1.0f / fmaxf(sqrtf(aq), 1e-12f);
            s_scale[1] = 1.0f / fmaxf(sqrtf(ak), 1e-12f);
        }
    }
    __syncthreads();
    if (tid < HDIM) {
        s_q[tid] *= s_scale[0];
        s_k[tid] *= s_scale[1];
    }
    __syncthreads();

    // 32 knn dots: 8 lanes per key
    {
        int g = tid >> 3, l8 = tid & 7;
        float p = 0.f;
        for (int d = l8; d < HDIM; d += 8) p += s_q[d] * s_knn[g * (2 * HDIM) + d];
        p += __shfl_xor(p, 1);
        p += __shfl_xor(p, 2);
        p += __shfl_xor(p, 4);
        if (l8 == 0) s_dot[g] = p * scaling;
    }
    // self dot (key 32)
    if (tid < 8) {
        float p = 0.f;
        for (int d = tid; d < HDIM; d += 8) p += s_q[d] * s_k[d];
        p += __shfl_xor(p, 1);
        p += __shfl_xor(p, 2);
        p += __shfl_xor(p, 4);
        if (tid == 0) s_dot[KNN] = p * scaling;
    }
    __syncthreads();

    // softmax over 33 (wave 0)
    if (tid < 64) {
        float x = (tid < 33) ? s_dot[tid] : -3.4e38f;
        float m = x;
        #pragma unroll
        for (int off = 32; off; off >>= 1) m = fmaxf(m, __shfl_xor(m, off));
        float e = (tid < 33) ? expf(x - m) : 0.f;
        float s = e;
        #pragma unroll
        for (int off = 32; off; off >>= 1) s += __shfl_xor(s, off);
        if (tid < 33) s_dot[tid] = e / s;
    }
    __syncthreads();

    // PV: out[d] = sum_k attn[k] * v[k][d]
    if (tid < HDIM) {
        float acc = s_dot[KNN] * s_v[tid];
        #pragma unroll 8
        for (int k = 0; k < KNN; ++k)
            acc += s_dot[k] * s_knn[k * (2 * HDIM) + HDIM + tid];
        out[(size_t)n * C_DIM + h * HDIM + tid] = acc;
    }
}

extern "C" void kernel_launch(void* const* d_in, const int* in_sizes, int n_in,
                              void* d_out, int out_size, void* d_ws, size_t ws_size,
                              hipStream_t stream)
{
    const float* x      = (const float*)d_in[0];
    const float* knn_kv = (const float*)d_in[1];
    const float* w_qkv  = (const float*)d_in[2];
    const float* b_qkv  = (const float*)d_in[3];
    const float* w_proj = (const float*)d_in[4];
    const float* b_proj = (const float*)d_in[5];
    float* out = (float*)d_out;

    float* qkv      = (float*)d_ws;                     // 4096*1584 f32
    float* attn_out = qkv + (size_t)N_POS * CQKV;       // 4096*528  f32

    dim3 g1((CQKV + 63) / 64, N_POS / 64);
    gemm_bt_kernel<<<g1, 256, 0, stream>>>(x, w_qkv, b_qkv, qkv, N_POS, CQKV, C_DIM);

    attn_kernel<<<dim3(NHEAD * N_POS), 256, 0, stream>>>(qkv, knn_kv, attn_out);

    dim3 g2((C_DIM + 63) / 64, N_POS / 64);
    gemm_bt_kernel<<<g2, 256, 0, stream>>>(attn_out, w_proj, b_proj, out, N_POS, C_DIM, C_DIM);
}

// Round 2
// 180.256 us; speedup vs baseline: 1.6710x; 1.6710x over previous
//
#include <hip/hip_runtime.h>
#include <hip/hip_bf16.h>
#include <math.h>

#define N_POS 4096
#define C_DIM 528
#define NHEAD 8
#define HDIM  66
#define KNN   32
#define CQKV  1584
#define KP    544      // 528 padded to 17*32
#define NP1   1664     // 1584 padded to 13*128
#define NP2   640      // 528 padded to 5*128

typedef __attribute__((ext_vector_type(8))) short short8;
typedef __attribute__((ext_vector_type(4))) float f32x4;
typedef __hip_bfloat16 bf16;

// ---------------------------------------------------------------------------
// Fused f32 -> bf16 conversion with zero padding to [Npad][KP] row-major.
// Covers x (4096x528 -> 4096x544), w_qkv (1584x528 -> 1664x544),
// w_proj (528x528 -> 640x544).
// ---------------------------------------------------------------------------
__global__ __launch_bounds__(256) void convpad3_kernel(
    const float* __restrict__ x, const float* __restrict__ wq,
    const float* __restrict__ wp,
    bf16* __restrict__ xb, bf16* __restrict__ wqb, bf16* __restrict__ wpb)
{
    int b = blockIdx.x;
    const float* src; bf16* dst; int Nr;
    if (b < N_POS)            { src = x;  dst = xb;  Nr = N_POS; }
    else if (b < N_POS + NP1) { b -= N_POS; src = wq; dst = wqb; Nr = CQKV; }
    else                      { b -= N_POS + NP1; src = wp; dst = wpb; Nr = C_DIM; }
    for (int c = threadIdx.x; c < KP; c += 256) {
        float v = (b < Nr && c < C_DIM) ? src[(size_t)b * C_DIM + c] : 0.0f;
        dst[(size_t)b * KP + c] = __float2bfloat16(v);
    }
}

// ---------------------------------------------------------------------------
// bf16 MFMA GEMM: C[m][n] = sum_k A[m][k]*B[n][k] + bias[n]  (f32 out)
// A: [*][KP] bf16 (rows cover grid.y*128), B: [*][KP] bf16 (rows cover
// grid.x*128, zero-padded). Tile 128x128xBK32, 4 waves (2x2), 16x16x32 MFMA,
// 4x4 fragments/wave. LDS slots are 16B units with XOR swizzle
// pc = c16 ^ (row&3) -> conflict-free ds_read_b128 / ds_write_b128.
// ---------------------------------------------------------------------------
__global__ __launch_bounds__(256) void gemm_mfma_kernel(
    const bf16* __restrict__ A, const bf16* __restrict__ B,
    const float* __restrict__ bias, float* __restrict__ C,
    int Nreal, int ldc)
{
    __shared__ short8 As[512];   // 128 rows x 4 x 16B = 8 KB
    __shared__ short8 Bs[512];

    const int tid  = threadIdx.x;
    const int lane = tid & 63;
    const int wid  = tid >> 6;
    const int bm = blockIdx.y * 128;
    const int bn = blockIdx.x * 128;

    // staging: thread covers (row=r0, c16=c0) and (row=r0+64, c16=c0)
    const int r0 = tid >> 2;
    const int c0 = tid & 3;
    const bf16* Ag = A + (size_t)(bm + r0) * KP + c0 * 8;
    const bf16* Bg = B + (size_t)(bn + r0) * KP + c0 * 8;
    const size_t roff = (size_t)64 * KP;

    short8 a0 = *(const short8*)(Ag);
    short8 a1 = *(const short8*)(Ag + roff);
    short8 b0 = *(const short8*)(Bg);
    short8 b1 = *(const short8*)(Bg + roff);

    const int w0 = r0 * 4 + (c0 ^ (r0 & 3));
    const int w1 = w0 + 256;   // row+64: (row&3) unchanged

    // fragment read slots
    const int wm = (wid >> 1) * 64;
    const int wn = (wid & 1) * 64;
    const int arow = wm + (lane & 15);
    const int brow = wn + (lane & 15);
    const int apc  = lane >> 4;
    const int aslot = arow * 4 + (apc ^ (arow & 3));
    const int bslot = brow * 4 + (apc ^ (brow & 3));

    f32x4 acc[4][4];
    #pragma unroll
    for (int i = 0; i < 4; ++i)
        #pragma unroll
        for (int j = 0; j < 4; ++j)
            acc[i][j] = (f32x4){0.f, 0.f, 0.f, 0.f};

    for (int k0 = 0;; k0 += 32) {
        As[w0] = a0; As[w1] = a1;
        Bs[w0] = b0; Bs[w1] = b1;
        __syncthreads();
        if (k0 + 32 < KP) {        // reg double-buffer: prefetch next K-tile
            const bf16* An = Ag + (k0 + 32);
            const bf16* Bn = Bg + (k0 + 32);
            a0 = *(const short8*)(An);
            a1 = *(const short8*)(An + roff);
            b0 = *(const short8*)(Bn);
            b1 = *(const short8*)(Bn + roff);
        }
        short8 af[4], bfr[4];
        #pragma unroll
        for (int f = 0; f < 4; ++f) af[f]  = As[aslot + f * 64];
        #pragma unroll
        for (int f = 0; f < 4; ++f) bfr[f] = Bs[bslot + f * 64];
        #pragma unroll
        for (int i = 0; i < 4; ++i)
            #pragma unroll
            for (int j = 0; j < 4; ++j)
                acc[i][j] = __builtin_amdgcn_mfma_f32_16x16x32_bf16(
                    af[i], bfr[j], acc[i][j], 0, 0, 0);
        if (k0 + 32 >= KP) break;
        __syncthreads();
    }

    // epilogue: C/D layout col=lane&15, row=(lane>>4)*4+reg  [m89/m91]
    #pragma unroll
    for (int i = 0; i < 4; ++i) {
        const int row = bm + wm + i * 16 + (lane >> 4) * 4;
        #pragma unroll
        for (int j = 0; j < 4; ++j) {
            const int col = bn + wn + j * 16 + (lane & 15);
            if (col < Nreal) {
                const float bv = bias[col];
                #pragma unroll
                for (int r = 0; r < 4; ++r)
                    C[(size_t)(row + r) * ldc + col] = acc[i][j][r] + bv;
            }
        }
    }
}

// ---------------------------------------------------------------------------
// Fused l2norm + 33-key attention. One block (256 thr) per (h, n).
// qkv: [N_POS][CQKV] f32; knn: [NHEAD][N_POS][KNN][2][HDIM] f32
// out: [N_POS][KP] bf16 (cols 528..543 zeroed by h==0 blocks)
// ---------------------------------------------------------------------------
__global__ __launch_bounds__(256) void attn_kernel(
    const float* __restrict__ qkv, const float* __restrict__ knn,
    bf16* __restrict__ out)
{
    const float scaling = 0.12309149097933272f;  // 66^-0.5

    int bid = blockIdx.x;
    int h = bid >> 12;
    int n = bid & 4095;
    int tid = threadIdx.x;

    __shared__ float s_knn[KNN * 2 * HDIM];
    __shared__ float s_q[HDIM], s_k[HDIM], s_v[HDIM];
    __shared__ float s_dot[KNN + 1];
    __shared__ float s_scale[2];

    {
        const float4* src = (const float4*)(knn + ((size_t)bid) * (KNN * 2 * HDIM));
        float4* dst = (float4*)s_knn;
        for (int i = tid; i < KNN * 2 * HDIM / 4; i += 256) dst[i] = src[i];
    }
    const float* qp = qkv + (size_t)n * CQKV + h * HDIM;
    if (tid < HDIM) {
        s_q[tid] = qp[tid];
        s_k[tid] = qp[C_DIM + tid];
        s_v[tid] = qp[2 * C_DIM + tid];
    }
    __syncthreads();

    if (tid < 64) {
        float aq = s_q[tid] * s_q[tid];
        float ak = s_k[tid] * s_k[tid];
        if (tid < 2) {
            aq += s_q[64 + tid] * s_q[64 + tid];
            ak += s_k[64 + tid] * s_k[64 + tid];
        }
        #pragma unroll
        for (int off = 32; off; off >>= 1) {
            aq += __shfl_xor(aq, off);
            ak += __shfl_xor(ak, off);
        }
        if (tid == 0) {
            s_scale[0] = 1.0f / fmaxf(sqrtf(aq), 1e-12f);
            s_scale[1] = 1.0f / fmaxf(sqrtf(ak), 1e-12f);
        }
    }
    __syncthreads();
    if (tid < HDIM) {
        s_q[tid] *= s_scale[0];
        s_k[tid] *= s_scale[1];
    }
    __syncthreads();

    {
        int g = tid >> 3, l8 = tid & 7;
        float p = 0.f;
        for (int d = l8; d < HDIM; d += 8) p += s_q[d] * s_knn[g * (2 * HDIM) + d];
        p += __shfl_xor(p, 1);
        p += __shfl_xor(p, 2);
        p += __shfl_xor(p, 4);
        if (l8 == 0) s_dot[g] = p * scaling;
    }
    if (tid < 8) {
        float p = 0.f;
        for (int d = tid; d < HDIM; d += 8) p += s_q[d] * s_k[d];
        p += __shfl_xor(p, 1);
        p += __shfl_xor(p, 2);
        p += __shfl_xor(p, 4);
        if (tid == 0) s_dot[KNN] = p * scaling;
    }
    __syncthreads();

    if (tid < 64) {
        float x = (tid < 33) ? s_dot[tid] : -3.4e38f;
        float m = x;
        #pragma unroll
        for (int off = 32; off; off >>= 1) m = fmaxf(m, __shfl_xor(m, off));
        float e = (tid < 33) ? expf(x - m) : 0.f;
        float s = e;
        #pragma unroll
        for (int off = 32; off; off >>= 1) s += __shfl_xor(s, off);
        if (tid < 33) s_dot[tid] = e / s;
    }
    __syncthreads();

    if (tid < HDIM) {
        float acc = s_dot[KNN] * s_v[tid];
        #pragma unroll 8
        for (int k = 0; k < KNN; ++k)
            acc += s_dot[k] * s_knn[k * (2 * HDIM) + HDIM + tid];
        out[(size_t)n * KP + h * HDIM + tid] = __float2bfloat16(acc);
    }
    if (h == 0 && tid < KP - C_DIM) {   // zero the K-pad columns once per row
        out[(size_t)n * KP + C_DIM + tid] = __float2bfloat16(0.0f);
    }
}

extern "C" void kernel_launch(void* const* d_in, const int* in_sizes, int n_in,
                              void* d_out, int out_size, void* d_ws, size_t ws_size,
                              hipStream_t stream)
{
    const float* x      = (const float*)d_in[0];
    const float* knn_kv = (const float*)d_in[1];
    const float* w_qkv  = (const float*)d_in[2];
    const float* b_qkv  = (const float*)d_in[3];
    const float* w_proj = (const float*)d_in[4];
    const float* b_proj = (const float*)d_in[5];
    float* out = (float*)d_out;

    char* ws = (char*)d_ws;
    float* qkv = (float*)ws;                                  // 4096*1584 f32 = 25,952,256 B
    bf16*  xb  = (bf16*)(ws + 25952256);                      // 4096*544*2 = 4,456,448 B
    bf16*  wqb = (bf16*)(ws + 25952256 + 4456448);            // 1664*544*2 = 1,810,432 B
    bf16*  wpb = (bf16*)(ws + 25952256 + 4456448 + 1810432);  // 640*544*2  =   696,320 B
    bf16*  ab  = (bf16*)(ws + 25952256 + 4456448 + 1810432 + 696320);  // 4096*544*2

    convpad3_kernel<<<N_POS + NP1 + NP2, 256, 0, stream>>>(x, w_qkv, w_proj, xb, wqb, wpb);

    gemm_mfma_kernel<<<dim3(NP1 / 128, N_POS / 128), 256, 0, stream>>>(
        xb, wqb, b_qkv, qkv, CQKV, CQKV);

    attn_kernel<<<dim3(NHEAD * N_POS), 256, 0, stream>>>(qkv, knn_kv, ab);

    gemm_mfma_kernel<<<dim3(NP2 / 128, N_POS / 128), 256, 0, stream>>>(
        ab, wpb, b_proj, out, C_DIM, C_DIM);
}